// Round 8
// baseline (13622.057 us; speedup 1.0000x reference)
//
#include <hip/hip_runtime.h>
#include <hip/hip_bf16.h>
#include <cstdint>
#include <cstddef>

#define DEV __device__ __forceinline__

typedef _Float16 h2v __attribute__((ext_vector_type(2)));
typedef _Float16 f16x8 __attribute__((ext_vector_type(8)));
typedef unsigned u4v __attribute__((ext_vector_type(4)));
typedef float f32x4 __attribute__((ext_vector_type(4)));

DEV float sigmoidf_(float x) { return 1.0f / (1.0f + __expf(-x)); }
DEV float tanhf_(float x) {
    float e = __expf(2.0f * x);
    return 1.0f - 2.0f / (e + 1.0f);
}

// Un-sinkable, un-rematerializable 16B load (resident weight fragments).
DEV u4v gload(const void* p) {
    u4v r;
    asm volatile("global_load_dwordx4 %0, %1, off\n\ts_waitcnt vmcnt(0)"
                 : "=v"(r) : "v"(p) : "memory");
    return r;
}

DEV f16x8 asF16(u4v v) { union { u4v u; f16x8 h; } c; c.u = v; return c.h; }

// LDS-only barrier: does NOT drain vmcnt; global stores stay in flight.
#define LDS_BARRIER() asm volatile("s_waitcnt lgkmcnt(0)\n\ts_barrier" ::: "memory")

#define MFMA(A, B, C) __builtin_amdgcn_mfma_f32_16x16x32_f16((A), (B), (C), 0, 0, 0)

// ---------------------------------------------------------------------------
// Pack 10 matrices (256x64 each) into MFMA B-fragments (f16):
//   frag(m, tile t, k-slice s): lane holds B[k = 32s + (lane>>4)*8 + j]
//                                         [n = 16t + (lane&15)],  j = 0..7
// m: 0-2 l1Whh, 3-5 l2Whh, 6-7 l1Wih (layers 1,2), 8-9 l2Wih (layers 1,2).
// ---------------------------------------------------------------------------
__global__ __launch_bounds__(256) void pack_w(
    const float* __restrict__ l1Whh, const float* __restrict__ l2Whh,
    const float* __restrict__ Wih12, const float* __restrict__ l2Wih,
    unsigned* __restrict__ wP)
{
    int idx = blockIdx.x * 256 + threadIdx.x;   // 10*8192 = 81920
    int m = idx >> 13;
    int w = idx & 8191;
    int t    = w >> 9;
    int s    = (w >> 8) & 1;
    int lane = (w >> 2) & 63;
    int jp   = w & 3;
    int gu = 16 * t + (lane & 15);
    int k  = 32 * s + (lane >> 4) * 8 + 2 * jp;

    const float* W;
    if (m < 3)      W = l1Whh + (size_t)m * 16384;
    else if (m < 6) W = l2Whh + (size_t)(m - 3) * 16384;
    else if (m < 8) W = Wih12 + (size_t)(m - 6) * 16384;
    else            W = l2Wih + (size_t)(m - 7) * 16384;   // layers 1,2

    const float* e = W + (size_t)gu * 64 + k;
    union { h2v h; unsigned u32; } c;
    c.h = (h2v){(_Float16)e[0], (_Float16)e[1]};
    wP[idx] = c.u32;
}

// ---------------------------------------------------------------------------
// Input projection (layer 0 of each stack only): xg[b,t,u*4+g] unit-major.
// ---------------------------------------------------------------------------
__global__ __launch_bounds__(256) void proj_kernel(
    const float* __restrict__ x, const float* __restrict__ Wih,
    const float* __restrict__ bias, const float* __restrict__ gate,
    float* __restrict__ xg, int D, int T)
{
    __shared__ float xS[16 * 64];
    int tb = T / 16;
    int b  = blockIdx.x / tb;
    int t0 = (blockIdx.x % tb) * 16;
    int tid = threadIdx.x;

    int n = 16 * D;
    for (int e = tid; e < n; e += 256) {
        int t = e / D;
        int i = e - t * D;
        float v = x[((size_t)(b * T + t0 + t)) * D + i];
        if (gate) v += gate[b * T + t0 + t];
        xS[t * D + i] = v;
    }
    __syncthreads();

    int g = tid;
    float acc[16];
    float bg = bias[g];
#pragma unroll
    for (int t = 0; t < 16; t++) acc[t] = bg;

    const float* wr = Wih + (size_t)g * D;
    for (int i = 0; i < D; i++) {
        float w = wr[i];
#pragma unroll
        for (int t = 0; t < 16; t++) acc[t] += xS[t * D + i] * w;
    }

    float* og = xg + ((size_t)(b * T + t0)) * 256 + (g & 63) * 4 + (g >> 6);
#pragma unroll
    for (int t = 0; t < 16; t++) og[(size_t)t * 256] = acc[t];
}

// ---------------------------------------------------------------------------
// Chunked 3-layer LSTM scan v23: MFMA matvec, LANE-LOCAL activations.
//
// v22 post-mortem: heaters killed the cold-clock ramp but power-limited the
// steady state (worse). Refined model: at 1-2 busy CUs the chip sits in a
// low DPM state; measured ~930ns/tick == the SERIAL CHAIN (~1000-1200 real
// cy) of ~5 dependent LDS hops + MFMA + act. Fix = fewer chain links:
//  * KEY: C-layout puts all 4 gates of unit u on lane u&15 (gu=u+64g ->
//    same col, tiles t=(u>>4)+4g). Batch b rides A-row 4b -> lanes 0-15
//    hold b0 cells, 16-31 hold b1 cells, elem0 of each C quad. The paW
//    scatter/gather LDS round-trip VANISHES: MFMA -> extract -> act -> h
//    all lane-local. Chain: h-write -> A-read -> 32 MFMA -> act -> write.
//  * pa2 (Wih preacts) gathered per tick BEHIND the A-read (data ready
//    since epoch head) - off the dependency chain. Scatter layout
//    [2r+b][g][u]: 4-way max conflicts.
//  * C quads extracted to scalars immediately -> live C ~16 regs; demand
//    ~210 fits the observed 216-236 grant ceiling -> no spill.
//  * No heaters (power-limit regression). Whh resident 128 VGPR, Wih in
//    LDS (epoch-amortized), RR=8 epochs, parity hchunk, 1 barrier/epoch.
// ---------------------------------------------------------------------------
#define RR 8

__global__
__attribute__((amdgpu_flat_work_group_size(192, 192), amdgpu_waves_per_eu(1, 1)))
void scan3_kernel(
    const float* __restrict__ xg, const unsigned* __restrict__ whhP,
    const unsigned* __restrict__ wihP, const float* __restrict__ bvec,
    const float* __restrict__ h0, const float* __restrict__ c0,
    float* __restrict__ Hout, int T)
{
    __shared__ __align__(16) u4v wihS[4096];                   // 64 KB Wih frags
    __shared__ __align__(16) _Float16 hchunk[2][3][RR][2][64]; // 12 KB
    __shared__ __align__(16) float pa2[2][2 * RR][4][64];      // 32 KB [l-1][2r+b][g][u]

    const int tid = threadIdx.x;
    const int l = tid >> 6, L = tid & 63;
    const int c16 = L & 15, q = L >> 4;
    const bool isAct = (L < 32);
    const int ab = q & 1;            // act-lane batch (valid when isAct)

    // stage Wih fragments (both layers) into LDS
    for (int i = tid; i < 4096; i += 192) wihS[i] = ((const u4v*)wihP)[i];

    // resident Whh B-fragments (128 VGPR)
    u4v whhB[32];
    {
        const u4v* wp = (const u4v*)whhP + (size_t)l * 2048;
#pragma unroll
        for (int i = 0; i < 32; i++) whhB[i] = gload(wp + i * 64 + L);
    }
    const u4v zq = {0u, 0u, 0u, 0u};

    // act-lane state: 4 cells (units c16+16k) of batch ab
    float cs[4] = {0.f, 0.f, 0.f, 0.f};
    if (isAct) {
#pragma unroll
        for (int k = 0; k < 4; k++) {
            int u = c16 + 16 * k;
            cs[k] = c0[l * 128 + ab * 64 + u];
            hchunk[1][l][RR - 1][ab][u] = (_Float16)h0[l * 128 + ab * 64 + u];
        }
    }
    float bg[16];
#pragma unroll
    for (int k = 0; k < 4; k++)
#pragma unroll
        for (int g = 0; g < 4; g++)
            bg[k * 4 + g] = (l > 0) ? bvec[l * 256 + g * 64 + c16 + 16 * k] : 0.f;

    // L0 x-preacts: depth-2 rolling prefetch, 4 units/lane (f32x4 = i,f,g,o)
    const f32x4* xpp = (const f32x4*)xg + (size_t)ab * T * 64;
    f32x4 xb[2][4];
    if (l == 0 && isAct) {
#pragma unroll
        for (int d = 0; d < 2; d++)
#pragma unroll
            for (int k = 0; k < 4; k++)
                xb[d][k] = xpp[(size_t)d * 64 + c16 + 16 * k];
    }
    float* ho = Hout + (size_t)ab * T * 64 + c16;

    __syncthreads();

    const int NC = T / RR;
    const f32x4 z4 = {0.f, 0.f, 0.f, 0.f};

    for (int e = 0; e < NC + 2; e++) {
        int m = e - l;
        if (m >= 0 && m < NC) {
            const int p = m & 1;
            const int base = m * RR;

            if (l > 0) {
                // ---- epoch-head GEMM: Wih(LDS) @ h_below, A rows = 2r+b ----
                int gr = c16 >> 1, gb = c16 & 1;
                f16x8 ga0 = *(const f16x8*)&hchunk[p][l - 1][gr][gb][q * 8];
                f16x8 ga1 = *(const f16x8*)&hchunk[p][l - 1][gr][gb][32 + q * 8];
                const u4v* wb = wihS + (size_t)(l - 1) * 2048 + L;
#pragma unroll
                for (int t = 0; t < 16; t++) {
                    f32x4 ax = MFMA(ga0, asF16(wb[(2 * t) * 64]), z4);
                    ax = MFMA(ga1, asF16(wb[(2 * t + 1) * 64]), ax);
                    int gu = 16 * t + c16, g = gu >> 6, uu = gu & 63;
                    // C rows 4q+j = (2r+b); scatter -> pa2[2r+b][g][u]
#pragma unroll
                    for (int j = 0; j < 4; j++)
                        pa2[l - 1][4 * q + j][g][uu] = ax[j];
                }
            }

            // ---- 8 ticks ----
#pragma unroll 2
            for (int r = 0; r < RR; r++) {
                const int tau = base + r;
                const int pp = (r == 0) ? (p ^ 1) : p;
                const int rp = (r == 0) ? (RR - 1) : (r - 1);

                // 1) own-h A-frags: batch b in row 4b (lanes c16==0 -> b0,
                //    c16==4 -> b1); k = q*8+j per k-slice. CRITICAL PATH.
                f16x8 a0 = asF16(zq), a1 = asF16(zq);
                if (c16 == 0 || c16 == 4) {
                    int bb = c16 >> 2;
                    a0 = *(const f16x8*)&hchunk[pp][l][rp][bb][q * 8];
                    a1 = *(const f16x8*)&hchunk[pp][l][rp][bb][32 + q * 8];
                }

                // 2) off-path operand fetch (pa2 ready since epoch head;
                //    xg prefetched 2 ticks ahead)
                float pv[16];
                f32x4 xv[4];
                if (isAct) {
                    if (l > 0) {
#pragma unroll
                        for (int k = 0; k < 4; k++)
#pragma unroll
                            for (int g = 0; g < 4; g++)
                                pv[k * 4 + g] = pa2[l - 1][2 * r + ab][g][c16 + 16 * k];
                    } else {
#pragma unroll
                        for (int k = 0; k < 4; k++) {
                            xv[k] = xb[r & 1][k];
                            int tp = tau + 2; if (tp > T - 1) tp = T - 1;
                            xb[r & 1][k] = xpp[(size_t)tp * 64 + c16 + 16 * k];
                        }
                    }
                }

                // 3) Whh matvec: tile t=k+4g holds gate g of unit c16+16k;
                //    extract elem0 immediately (C-live stays ~16 regs)
                float pA[16];
#pragma unroll
                for (int k = 0; k < 4; k++)
#pragma unroll
                    for (int g = 0; g < 4; g++) {
                        int t = k + 4 * g;
                        f32x4 aw = MFMA(a0, asF16(whhB[2 * t]), z4);
                        aw = MFMA(a1, asF16(whhB[2 * t + 1]), aw);
                        pA[k * 4 + g] = aw[0];
                    }

                // 4) lane-local activations (4 cells/lane on 32 lanes) + h
                if (isAct) {
#pragma unroll
                    for (int k = 0; k < 4; k++) {
                        float aI, aF, aG, aO;
                        if (l == 0) {
                            aI = pA[k * 4 + 0] + xv[k][0];
                            aF = pA[k * 4 + 1] + xv[k][1];
                            aG = pA[k * 4 + 2] + xv[k][2];
                            aO = pA[k * 4 + 3] + xv[k][3];
                        } else {
                            aI = pA[k * 4 + 0] + pv[k * 4 + 0] + bg[k * 4 + 0];
                            aF = pA[k * 4 + 1] + pv[k * 4 + 1] + bg[k * 4 + 1];
                            aG = pA[k * 4 + 2] + pv[k * 4 + 2] + bg[k * 4 + 2];
                            aO = pA[k * 4 + 3] + pv[k * 4 + 3] + bg[k * 4 + 3];
                        }
                        cs[k] = sigmoidf_(aF) * cs[k] + sigmoidf_(aI) * tanhf_(aG);
                        float hv = sigmoidf_(aO) * tanhf_(cs[k]);
                        hchunk[p][l][r][ab][c16 + 16 * k] = (_Float16)hv;
                        if (l == 2) ho[(size_t)tau * 64 + 16 * k] = hv;
                    }
                }
            }
        }
        LDS_BARRIER();   // publish hchunk writes; epoch parity flip
    }
}

// ---------------------------------------------------------------------------
// Hc[b, {max,mean,std(ddof=1)}, t] over hidden dim (64). One wave per (b,t).
// ---------------------------------------------------------------------------
__global__ __launch_bounds__(256) void stats_kernel(
    const float* __restrict__ H, float* __restrict__ Hc, int T)
{
    int wid = threadIdx.x >> 6, lane = threadIdx.x & 63;
    int bt = blockIdx.x * 4 + wid;
    int b = bt / T, t = bt - b * T;

    float x = H[(size_t)bt * 64 + lane];
    float mx = x, sm = x;
#pragma unroll
    for (int m = 32; m >= 1; m >>= 1) {
        mx = fmaxf(mx, __shfl_xor(mx, m));
        sm += __shfl_xor(sm, m);
    }
    float mean = sm * (1.0f / 64.0f);
    float d = x - mean;
    float ss = d * d;
#pragma unroll
    for (int m = 32; m >= 1; m >>= 1) ss += __shfl_xor(ss, m);
    float sd = sqrtf(ss * (1.0f / 63.0f));

    if (lane == 0) {
        float* o = Hc + (size_t)b * 3 * T;
        o[0 * T + t] = mx;
        o[1 * T + t] = mean;
        o[2 * T + t] = sd;
    }
}

// ---------------------------------------------------------------------------
// Middle conv/BN chain, single workgroup (1024 threads).
// ---------------------------------------------------------------------------
template <int CIN, int COUT, int MODE>
DEV void conv_bn_stage(const float* __restrict__ in, const float* __restrict__ w,
                       const float* __restrict__ bias, float* __restrict__ out,
                       float* __restrict__ gate, int T, int tid,
                       float* rs, float* rq, float* stm, float* sti)
{
    float lsum[COUT], lss[COUT];
#pragma unroll
    for (int oc = 0; oc < COUT; oc++) { lsum[oc] = 0.f; lss[oc] = 0.f; }

    for (int k = 0; k < 8; k++) {
        int p = tid + k * 1024;
        int b = p / T;
        int t = p - b * T;
        float acc[COUT];
#pragma unroll
        for (int oc = 0; oc < COUT; oc++) acc[oc] = bias[oc];
#pragma unroll
        for (int ic = 0; ic < CIN; ic++) {
            const float* row = in + ((size_t)b * CIN + ic) * T;
            float xv[11];
#pragma unroll
            for (int kk = 0; kk < 11; kk++) {
                int tt = t + kk - 5;
                xv[kk] = (tt >= 0 && tt < T) ? row[tt] : 0.f;
            }
#pragma unroll
            for (int oc = 0; oc < COUT; oc++) {
                const float* wr = w + ((size_t)oc * CIN + ic) * 11;
#pragma unroll
                for (int kk = 0; kk < 11; kk++) acc[oc] += xv[kk] * wr[kk];
            }
        }
#pragma unroll
        for (int oc = 0; oc < COUT; oc++) {
            out[((size_t)b * COUT + oc) * T + t] = acc[oc];
            lsum[oc] += acc[oc];
            lss[oc] += acc[oc] * acc[oc];
        }
    }
    __syncthreads();

    int lane = tid & 63, wid = tid >> 6;
#pragma unroll
    for (int oc = 0; oc < COUT; oc++) {
        float s = lsum[oc], qq = lss[oc];
#pragma unroll
        for (int m = 32; m >= 1; m >>= 1) {
            s += __shfl_xor(s, m);
            qq += __shfl_xor(qq, m);
        }
        if (lane == 0) { rs[wid] = s; rq[wid] = qq; }
        __syncthreads();
        if (tid == 0) {
            float S = 0.f, Q = 0.f;
            for (int i = 0; i < 16; i++) { S += rs[i]; Q += rq[i]; }
            float m_ = S / (float)(2 * T);
            float v = Q / (float)(2 * T) - m_ * m_;
            stm[oc] = m_;
            sti[oc] = rsqrtf(v + 1e-5f);
        }
        __syncthreads();
    }

    for (int k = 0; k < 8; k++) {
        int p = tid + k * 1024;
        int b = p / T;
        int t = p - b * T;
#pragma unroll
        for (int oc = 0; oc < COUT; oc++) {
            size_t idx = ((size_t)b * COUT + oc) * T + t;
            float v = (out[idx] - stm[oc]) * sti[oc];
            if (MODE == 0) out[idx] = fmaxf(v, 0.f);
            else           gate[p] = sigmoidf_(v);
        }
    }
    __syncthreads();
}

__global__ __launch_bounds__(1024) void middle_kernel(
    const float* __restrict__ Hc,
    const float* __restrict__ w1, const float* __restrict__ b1,
    const float* __restrict__ w2, const float* __restrict__ b2,
    const float* __restrict__ w3, const float* __restrict__ b3,
    const float* __restrict__ w4, const float* __restrict__ b4,
    float* __restrict__ bufA, float* __restrict__ bufB,
    float* __restrict__ gate, int T)
{
    __shared__ float rs[16], rq[16], stm[8], sti[8];
    int tid = threadIdx.x;
    conv_bn_stage<3, 3, 0>(Hc,   w1, b1, bufA, nullptr, T, tid, rs, rq, stm, sti);
    conv_bn_stage<3, 5, 0>(bufA, w2, b2, bufB, nullptr, T, tid, rs, rq, stm, sti);
    conv_bn_stage<5, 5, 0>(bufB, w3, b3, bufA, nullptr, T, tid, rs, rq, stm, sti);
    conv_bn_stage<5, 1, 1>(bufA, w4, b4, bufB, gate,    T, tid, rs, rq, stm, sti);
}

// ---------------------------------------------------------------------------
// Head: y = sigmoid(fc2(fc1(out2))). One wave per (b,t).
// ---------------------------------------------------------------------------
__global__ __launch_bounds__(256) void final_kernel(
    const float* __restrict__ out2, const float* __restrict__ fc1w,
    const float* __restrict__ fc1b, const float* __restrict__ fc2w,
    const float* __restrict__ fc2b, float* __restrict__ out, int T)
{
    int wid = threadIdx.x >> 6, lane = threadIdx.x & 63;
    int bt = blockIdx.x * 4 + wid;

    const float* o2 = out2 + (size_t)bt * 64;
    float acc = fc1b[lane];
    const float* wr = fc1w + (size_t)lane * 64;
#pragma unroll
    for (int k = 0; k < 64; k++) acc += o2[k] * wr[k];

    float p = acc * fc2w[lane];
#pragma unroll
    for (int m = 32; m >= 1; m >>= 1) p += __shfl_xor(p, m);

    if (lane == 0) out[bt] = sigmoidf_(p + fc2b[0]);
}

// ---------------------------------------------------------------------------
extern "C" void kernel_launch(void* const* d_in, const int* in_sizes, int n_in,
                              void* d_out, int out_size, void* d_ws, size_t ws_size,
                              hipStream_t stream)
{
    const float* data  = (const float*)d_in[0];
    const float* h01   = (const float*)d_in[1];
    const float* c01   = (const float*)d_in[2];
    const float* h02   = (const float*)d_in[3];
    const float* c02   = (const float*)d_in[4];
    const float* Wih0  = (const float*)d_in[5];
    const float* Wih12 = (const float*)d_in[6];
    const float* l1Whh = (const float*)d_in[7];
    const float* l1b   = (const float*)d_in[8];
    const float* l2Wih = (const float*)d_in[9];
    const float* l2Whh = (const float*)d_in[10];
    const float* l2b   = (const float*)d_in[11];
    const float* cw1 = (const float*)d_in[12]; const float* cb1 = (const float*)d_in[13];
    const float* cw2 = (const float*)d_in[14]; const float* cb2 = (const float*)d_in[15];
    const float* cw3 = (const float*)d_in[16]; const float* cb3 = (const float*)d_in[17];
    const float* cw4 = (const float*)d_in[18]; const float* cb4 = (const float*)d_in[19];
    const float* fc1w = (const float*)d_in[20]; const float* fc1b = (const float*)d_in[21];
    const float* fc2w = (const float*)d_in[22]; const float* fc2b = (const float*)d_in[23];
    float* out = (float*)d_out;

    const int T = in_sizes[0] / (2 * 40);   // 4096
    const int B = 2;

    float* ws   = (float*)d_ws;
    float* xg   = ws;                                // B*T*256
    float* seqA = xg   + (size_t)B * T * 256;        // B*T*64
    float* seqB = seqA + (size_t)B * T * 64;         // B*T*64
    float* Hc   = seqB + (size_t)B * T * 64;         // B*3*T
    float* bufA = Hc   + (size_t)B * 3 * T;          // B*5*T
    float* bufB = bufA + (size_t)B * 5 * T;          // B*5*T
    float* gate = bufB + (size_t)B * 5 * T;          // B*T
    unsigned* wP = (unsigned*)(gate + (size_t)B * T); // 10*8192 u32

    dim3 pg(B * (T / 16)), pb(256);

    pack_w<<<320, 256, 0, stream>>>(l1Whh, l2Whh, Wih12, l2Wih, wP);

    // ---- LSTM1: proj layer0 + MFMA scan (1 block, both batches) ----
    proj_kernel<<<pg, pb, 0, stream>>>(data, Wih0, l1b, nullptr, xg, 40, T);
    scan3_kernel<<<1, 192, 0, stream>>>(xg, wP, wP + 6 * 8192, l1b, h01, c01, seqA, T);

    // ---- temporal-attention gate ----
    stats_kernel<<<(2 * T) / 4, 256, 0, stream>>>(seqA, Hc, T);
    middle_kernel<<<1, 1024, 0, stream>>>(Hc, cw1, cb1, cw2, cb2, cw3, cb3, cw4, cb4,
                                          bufA, bufB, gate, T);

    // ---- LSTM2: proj layer0 (gate folded) + MFMA scan ----
    proj_kernel<<<pg, pb, 0, stream>>>(seqA, l2Wih, l2b, gate, xg, 64, T);
    scan3_kernel<<<1, 192, 0, stream>>>(xg, wP + 3 * 8192, wP + 8 * 8192, l2b, h02, c02, seqB, T);

    // ---- head ----
    final_kernel<<<(2 * T) / 4, 256, 0, stream>>>(seqB, fc1w, fc1b, fc2w, fc2b, out, T);
}